// Round 1
// baseline (4191.524 us; speedup 1.0000x reference)
//
#include <hip/hip_runtime.h>

// ---------------- degree / norm prep ----------------

__global__ void deg_kernel(const int* __restrict__ dst, float* __restrict__ deg, int E) {
    int i = blockIdx.x * blockDim.x + threadIdx.x;
    if (i < E) atomicAdd(&deg[dst[i]], 1.0f);
}

__global__ void dinv_kernel(float* __restrict__ deg, int N) {
    int i = blockIdx.x * blockDim.x + threadIdx.x;
    if (i < N) deg[i] = rsqrtf(deg[i] + 1.0f);   // +1 = self-loop; deg>=1 always
}

__global__ void norm_kernel(const int* __restrict__ src, const int* __restrict__ dst,
                            const float* __restrict__ dinv, float* __restrict__ norm, int E) {
    int i = blockIdx.x * blockDim.x + threadIdx.x;
    if (i < E) norm[i] = dinv[src[i]] * dinv[dst[i]];
}

// ---------------- GEMM: Y[N,64] = X[N,K] @ W[K,64] ----------------

template <int K>
__global__ __launch_bounds__(256) void gemm_kernel(const float* __restrict__ X,
                                                   const float* __restrict__ W,
                                                   float* __restrict__ Y, int N) {
    __shared__ float Ws[K * 64];
    for (int i = threadIdx.x; i < K * 64; i += 256) Ws[i] = W[i];
    __syncthreads();
    int node = blockIdx.x * 16 + (threadIdx.x >> 4);
    int j4 = (threadIdx.x & 15) * 4;
    if (node >= N) return;
    const float* xr = X + (size_t)node * K;
    float4 acc = make_float4(0.f, 0.f, 0.f, 0.f);
#pragma unroll 16
    for (int k = 0; k < K; ++k) {
        float xv = xr[k];
        float4 wv = *(const float4*)&Ws[k * 64 + j4];
        acc.x += xv * wv.x;
        acc.y += xv * wv.y;
        acc.z += xv * wv.z;
        acc.w += xv * wv.w;
    }
    *(float4*)&Y[(size_t)node * 64 + j4] = acc;
}

// ---------------- self-loop init: agg[n] = h[n] * dinv[n]^2 ----------------

__global__ void selfloop_kernel(const float* __restrict__ h, const float* __restrict__ dinv,
                                float* __restrict__ agg, int N) {
    int t = blockIdx.x * blockDim.x + threadIdx.x;
    if (t >= N * 16) return;
    int node = t >> 4;
    int c = (t & 15) * 4;
    float w = dinv[node];
    w *= w;
    float4 v = *(const float4*)&h[(size_t)node * 64 + c];
    v.x *= w; v.y *= w; v.z *= w; v.w *= w;
    *(float4*)&agg[(size_t)node * 64 + c] = v;
}

// ---------------- edge scatter: agg[dst] += h[src] * norm ----------------

__global__ void scatter_kernel(const float* __restrict__ h, const int* __restrict__ src,
                               const int* __restrict__ dst, const float* __restrict__ norm,
                               float* __restrict__ agg, int E) {
    int t = blockIdx.x * blockDim.x + threadIdx.x;
    if (t >= E * 16) return;
    int e = t >> 4;
    int c = (t & 15) * 4;
    int s = src[e];
    int d = dst[e];
    float w = norm[e];
    float4 v = *(const float4*)&h[(size_t)s * 64 + c];
    float* a = &agg[(size_t)d * 64 + c];
    atomicAdd(a + 0, v.x * w);
    atomicAdd(a + 1, v.y * w);
    atomicAdd(a + 2, v.z * w);
    atomicAdd(a + 3, v.w * w);
}

// ---------------- bias + (optional) relu ----------------

template <bool RELU>
__global__ void bias_act_kernel(float* __restrict__ agg, const float* __restrict__ b, int total) {
    int i = blockIdx.x * blockDim.x + threadIdx.x;
    if (i >= total) return;
    float v = agg[i] + b[i & 63];
    if (RELU) v = fmaxf(v, 0.f);
    agg[i] = v;
}

// ---------------- pooling fused with final projection ----------------

__global__ void pool_kernel(const float* __restrict__ h, const int* __restrict__ batch,
                            const float* __restrict__ Wl, float* __restrict__ gsum,
                            float* __restrict__ gcnt, int N) {
    __shared__ float wl[64];
    if (threadIdx.x < 64) wl[threadIdx.x] = Wl[threadIdx.x];
    __syncthreads();
    int n = blockIdx.x * blockDim.x + threadIdx.x;
    if (n >= N) return;
    const float* hr = &h[(size_t)n * 64];
    float s = 0.f;
#pragma unroll
    for (int k = 0; k < 64; ++k) s += hr[k] * wl[k];
    int g = batch[n];
    atomicAdd(&gsum[g], s);
    atomicAdd(&gcnt[g], 1.0f);
}

__global__ void out_kernel(const float* __restrict__ gsum, const float* __restrict__ gcnt,
                           const float* __restrict__ bl, float* __restrict__ out, int G) {
    int g = blockIdx.x * blockDim.x + threadIdx.x;
    if (g < G) out[g] = gsum[g] / fmaxf(gcnt[g], 1.0f) + bl[0];
}

// ---------------- launcher ----------------

extern "C" void kernel_launch(void* const* d_in, const int* in_sizes, int n_in,
                              void* d_out, int out_size, void* d_ws, size_t ws_size,
                              hipStream_t stream) {
    const float* x   = (const float*)d_in[0];
    const int*   ei  = (const int*)d_in[1];
    const int*   bat = (const int*)d_in[2];
    const float* W1  = (const float*)d_in[3];
    const float* b1  = (const float*)d_in[4];
    const float* W2  = (const float*)d_in[5];
    const float* b2  = (const float*)d_in[6];
    const float* W3  = (const float*)d_in[7];
    const float* b3  = (const float*)d_in[8];
    const float* Wl  = (const float*)d_in[9];
    const float* bl  = (const float*)d_in[10];

    const int N = in_sizes[0] / 128;   // 100000
    const int E = in_sizes[1] / 2;     // 1600000
    const int G = out_size;            // 1000

    const int* src = ei;
    const int* dst = ei + E;

    float* dinv = (float*)d_ws;                  // N
    float* norm = dinv + N;                      // E
    float* bufA = norm + E;                      // N*64
    float* bufB = bufA + (size_t)N * 64;         // N*64
    float* gsum = bufB + (size_t)N * 64;         // G
    float* gcnt = gsum + G;                      // G

    hipMemsetAsync(dinv, 0, (size_t)N * sizeof(float), stream);
    hipMemsetAsync(gsum, 0, (size_t)2 * G * sizeof(float), stream);

    deg_kernel<<<(E + 255) / 256, 256, 0, stream>>>(dst, dinv, E);
    dinv_kernel<<<(N + 255) / 256, 256, 0, stream>>>(dinv, N);
    norm_kernel<<<(E + 255) / 256, 256, 0, stream>>>(src, dst, dinv, norm, E);

    const int gemmGrid = (N + 15) / 16;
    const int slGrid   = (N * 16 + 255) / 256;
    const int scGrid   = (int)(((size_t)E * 16 + 255) / 256);
    const int baGrid   = (int)(((size_t)N * 64 + 255) / 256);

    // ---- layer 1 ----
    gemm_kernel<128><<<gemmGrid, 256, 0, stream>>>(x, W1, bufA, N);
    selfloop_kernel<<<slGrid, 256, 0, stream>>>(bufA, dinv, bufB, N);
    scatter_kernel<<<scGrid, 256, 0, stream>>>(bufA, src, dst, norm, bufB, E);
    bias_act_kernel<true><<<baGrid, 256, 0, stream>>>(bufB, b1, N * 64);

    // ---- layer 2 ----
    gemm_kernel<64><<<gemmGrid, 256, 0, stream>>>(bufB, W2, bufA, N);
    selfloop_kernel<<<slGrid, 256, 0, stream>>>(bufA, dinv, bufB, N);
    scatter_kernel<<<scGrid, 256, 0, stream>>>(bufA, src, dst, norm, bufB, E);
    bias_act_kernel<true><<<baGrid, 256, 0, stream>>>(bufB, b2, N * 64);

    // ---- layer 3 ----
    gemm_kernel<64><<<gemmGrid, 256, 0, stream>>>(bufB, W3, bufA, N);
    selfloop_kernel<<<slGrid, 256, 0, stream>>>(bufA, dinv, bufB, N);
    scatter_kernel<<<scGrid, 256, 0, stream>>>(bufA, src, dst, norm, bufB, E);
    bias_act_kernel<false><<<baGrid, 256, 0, stream>>>(bufB, b3, N * 64);

    // ---- pool + project ----
    pool_kernel<<<(N + 255) / 256, 256, 0, stream>>>(bufB, bat, Wl, gsum, gcnt, N);
    out_kernel<<<(G + 255) / 256, 256, 0, stream>>>(gsum, gcnt, bl, (float*)d_out, G);
}

// Round 2
// 643.030 us; speedup vs baseline: 6.5184x; 6.5184x over previous
//
#include <hip/hip_runtime.h>

// =============== CSR build ===============

__global__ void hist_kernel(const int* __restrict__ dst, int* __restrict__ cnt, int E) {
    int i = blockIdx.x * blockDim.x + threadIdx.x;
    if (i < E) atomicAdd(&cnt[dst[i]], 1);
}

// A: per-1024-chunk sums
__global__ void scan_sums(const int* __restrict__ cnt, int* __restrict__ sums, int N) {
    __shared__ int lds[4];
    int base = blockIdx.x * 1024;
    int s = 0;
    for (int i = threadIdx.x; i < 1024; i += 256) {
        int idx = base + i;
        if (idx < N) s += cnt[idx];
    }
    for (int d = 32; d; d >>= 1) s += __shfl_down(s, d);
    int wid = threadIdx.x >> 6;
    if ((threadIdx.x & 63) == 0) lds[wid] = s;
    __syncthreads();
    if (threadIdx.x == 0) sums[blockIdx.x] = lds[0] + lds[1] + lds[2] + lds[3];
}

// B: exclusive scan of chunk sums (nb ~ 98, serial is fine)
__global__ void scan_offsets(int* __restrict__ sums, int nb) {
    if (threadIdx.x == 0 && blockIdx.x == 0) {
        int run = 0;
        for (int i = 0; i < nb; ++i) { int v = sums[i]; sums[i] = run; run += v; }
    }
}

// C: per-chunk exclusive scan -> rowptr
__global__ __launch_bounds__(256) void scan_write(const int* __restrict__ cnt,
                                                  const int* __restrict__ sums,
                                                  int* __restrict__ rowptr, int N, int E) {
    __shared__ int lds[256];
    int base = blockIdx.x * 1024;
    int off = sums[blockIdx.x];
    for (int c = 0; c < 4; ++c) {
        int idx = base + c * 256 + threadIdx.x;
        int v = (idx < N) ? cnt[idx] : 0;
        lds[threadIdx.x] = v;
        __syncthreads();
        for (int d = 1; d < 256; d <<= 1) {
            int t = (threadIdx.x >= d) ? lds[threadIdx.x - d] : 0;
            __syncthreads();
            lds[threadIdx.x] += t;
            __syncthreads();
        }
        int incl = lds[threadIdx.x];
        if (idx < N) rowptr[idx] = off + incl - v;
        off += lds[255];
        __syncthreads();
    }
    if (blockIdx.x == 0 && threadIdx.x == 0) rowptr[N] = E;
}

__global__ void fill_kernel(const int* __restrict__ src, const int* __restrict__ dst,
                            const int* __restrict__ rowptr, int* __restrict__ cur,
                            int* __restrict__ csr, int E) {
    int e = blockIdx.x * blockDim.x + threadIdx.x;
    if (e < E) {
        int d = dst[e];
        int slot = rowptr[d] + atomicAdd(&cur[d], 1);
        csr[slot] = src[e];
    }
}

// =============== GEMM: Y[N,64] = (X[N,K] @ W[K,64]) * dinv[row] ===============

template <int K>
__global__ __launch_bounds__(256) void gemm_kernel(const float* __restrict__ X,
                                                   const float* __restrict__ W,
                                                   const int* __restrict__ rowptr,
                                                   float* __restrict__ Y, int N) {
    __shared__ float Ws[K * 64];
    for (int i = threadIdx.x; i < K * 64; i += 256) Ws[i] = W[i];
    __syncthreads();
    int node = blockIdx.x * 16 + (threadIdx.x >> 4);
    int j4 = (threadIdx.x & 15) * 4;
    if (node >= N) return;
    const float* xr = X + (size_t)node * K;
    float4 acc = make_float4(0.f, 0.f, 0.f, 0.f);
#pragma unroll 16
    for (int k = 0; k < K; ++k) {
        float xv = xr[k];
        float4 wv = *(const float4*)&Ws[k * 64 + j4];
        acc.x += xv * wv.x;
        acc.y += xv * wv.y;
        acc.z += xv * wv.z;
        acc.w += xv * wv.w;
    }
    float deg = (float)(rowptr[node + 1] - rowptr[node]);
    float w = rsqrtf(deg + 1.0f);
    acc.x *= w; acc.y *= w; acc.z *= w; acc.w *= w;
    *(float4*)&Y[(size_t)node * 64 + j4] = acc;
}

// =============== aggregate: out[d] = relu?(dinv[d]*(g[d] + sum g[src]) + b) ===============

template <bool RELU>
__global__ __launch_bounds__(256) void agg_kernel(const float* __restrict__ g,
                                                  const int* __restrict__ rowptr,
                                                  const int* __restrict__ csr,
                                                  const float* __restrict__ bias,
                                                  float* __restrict__ out, int N) {
    int t = blockIdx.x * blockDim.x + threadIdx.x;
    int node = t >> 4;
    if (node >= N) return;
    int c = (t & 15) * 4;
    int beg = rowptr[node], end = rowptr[node + 1];
    float4 acc = *(const float4*)&g[(size_t)node * 64 + c];   // self-loop term
    for (int j = beg; j < end; ++j) {
        int s = csr[j];
        float4 v = *(const float4*)&g[(size_t)s * 64 + c];
        acc.x += v.x; acc.y += v.y; acc.z += v.z; acc.w += v.w;
    }
    float w = rsqrtf((float)(end - beg) + 1.0f);
    float4 bb = *(const float4*)&bias[c];
    acc.x = acc.x * w + bb.x;
    acc.y = acc.y * w + bb.y;
    acc.z = acc.z * w + bb.z;
    acc.w = acc.w * w + bb.w;
    if (RELU) {
        acc.x = fmaxf(acc.x, 0.f); acc.y = fmaxf(acc.y, 0.f);
        acc.z = fmaxf(acc.z, 0.f); acc.w = fmaxf(acc.w, 0.f);
    }
    *(float4*)&out[(size_t)node * 64 + c] = acc;
}

// =============== pooling fused with final projection ===============

__global__ void pool_kernel(const float* __restrict__ h, const int* __restrict__ batch,
                            const float* __restrict__ Wl, float* __restrict__ gsum,
                            float* __restrict__ gcnt, int N) {
    __shared__ float wl[64];
    if (threadIdx.x < 64) wl[threadIdx.x] = Wl[threadIdx.x];
    __syncthreads();
    int n = blockIdx.x * blockDim.x + threadIdx.x;
    if (n >= N) return;
    const float* hr = &h[(size_t)n * 64];
    float s = 0.f;
#pragma unroll
    for (int k = 0; k < 64; ++k) s += hr[k] * wl[k];
    int gidx = batch[n];
    atomicAdd(&gsum[gidx], s);
    atomicAdd(&gcnt[gidx], 1.0f);
}

__global__ void out_kernel(const float* __restrict__ gsum, const float* __restrict__ gcnt,
                           const float* __restrict__ bl, float* __restrict__ out, int G) {
    int g = blockIdx.x * blockDim.x + threadIdx.x;
    if (g < G) out[g] = gsum[g] / fmaxf(gcnt[g], 1.0f) + bl[0];
}

// =============== launcher ===============

extern "C" void kernel_launch(void* const* d_in, const int* in_sizes, int n_in,
                              void* d_out, int out_size, void* d_ws, size_t ws_size,
                              hipStream_t stream) {
    const float* x   = (const float*)d_in[0];
    const int*   ei  = (const int*)d_in[1];
    const int*   bat = (const int*)d_in[2];
    const float* W1  = (const float*)d_in[3];
    const float* b1  = (const float*)d_in[4];
    const float* W2  = (const float*)d_in[5];
    const float* b2  = (const float*)d_in[6];
    const float* W3  = (const float*)d_in[7];
    const float* b3  = (const float*)d_in[8];
    const float* Wl  = (const float*)d_in[9];
    const float* bl  = (const float*)d_in[10];

    const int N = in_sizes[0] / 128;   // 100000
    const int E = in_sizes[1] / 2;     // 1600000
    const int G = out_size;            // 1000

    const int* src = ei;
    const int* dst = ei + E;

    // workspace layout
    int*   cnt    = (int*)d_ws;                        // N   (histogram, then cursor)
    int*   rowptr = cnt + N;                           // N+1
    int*   sums   = rowptr + (N + 1);                  // 1024
    int*   csr    = sums + 1024;                       // E
    float* bufA   = (float*)(csr + E);                 // N*64
    float* bufB   = bufA + (size_t)N * 64;             // N*64
    float* gsum   = bufB + (size_t)N * 64;             // G
    float* gcnt   = gsum + G;                          // G

    const int nb = (N + 1023) / 1024;

    // ---- CSR build ----
    hipMemsetAsync(cnt, 0, (size_t)N * sizeof(int), stream);
    hist_kernel<<<(E + 255) / 256, 256, 0, stream>>>(dst, cnt, E);
    scan_sums<<<nb, 256, 0, stream>>>(cnt, sums, N);
    scan_offsets<<<1, 64, 0, stream>>>(sums, nb);
    scan_write<<<nb, 256, 0, stream>>>(cnt, sums, rowptr, N, E);
    hipMemsetAsync(cnt, 0, (size_t)N * sizeof(int), stream);   // reuse as cursor
    fill_kernel<<<(E + 255) / 256, 256, 0, stream>>>(src, dst, rowptr, cnt, csr, E);

    hipMemsetAsync(gsum, 0, (size_t)2 * G * sizeof(float), stream);

    const int gemmGrid = (N + 15) / 16;
    const int aggGrid  = (N * 16 + 255) / 256;

    // ---- layer 1 ----
    gemm_kernel<128><<<gemmGrid, 256, 0, stream>>>(x, W1, rowptr, bufA, N);
    agg_kernel<true><<<aggGrid, 256, 0, stream>>>(bufA, rowptr, csr, b1, bufB, N);
    // ---- layer 2 ----
    gemm_kernel<64><<<gemmGrid, 256, 0, stream>>>(bufB, W2, rowptr, bufA, N);
    agg_kernel<true><<<aggGrid, 256, 0, stream>>>(bufA, rowptr, csr, b2, bufB, N);
    // ---- layer 3 ----
    gemm_kernel<64><<<gemmGrid, 256, 0, stream>>>(bufB, W3, rowptr, bufA, N);
    agg_kernel<false><<<aggGrid, 256, 0, stream>>>(bufA, rowptr, csr, b3, bufB, N);

    // ---- pool + project ----
    pool_kernel<<<(N + 255) / 256, 256, 0, stream>>>(bufB, bat, Wl, gsum, gcnt, N);
    out_kernel<<<(G + 255) / 256, 256, 0, stream>>>(gsum, gcnt, bl, (float*)d_out, G);
}

// Round 4
// 495.785 us; speedup vs baseline: 8.4543x; 1.2970x over previous
//
#include <hip/hip_runtime.h>

// =============== CSR build ===============

__global__ void hist_kernel(const int* __restrict__ dst, int* __restrict__ cnt, int E) {
    int i = blockIdx.x * blockDim.x + threadIdx.x;
    if (i < E) atomicAdd(&cnt[dst[i]], 1);
}

__global__ void scan_sums(const int* __restrict__ cnt, int* __restrict__ sums, int N) {
    __shared__ int lds[4];
    int base = blockIdx.x * 1024;
    int s = 0;
    for (int i = threadIdx.x; i < 1024; i += 256) {
        int idx = base + i;
        if (idx < N) s += cnt[idx];
    }
    for (int d = 32; d; d >>= 1) s += __shfl_down(s, d);
    int wid = threadIdx.x >> 6;
    if ((threadIdx.x & 63) == 0) lds[wid] = s;
    __syncthreads();
    if (threadIdx.x == 0) sums[blockIdx.x] = lds[0] + lds[1] + lds[2] + lds[3];
}

__global__ void scan_offsets(int* __restrict__ sums, int nb) {
    if (threadIdx.x == 0 && blockIdx.x == 0) {
        int run = 0;
        for (int i = 0; i < nb; ++i) { int v = sums[i]; sums[i] = run; run += v; }
    }
}

__global__ __launch_bounds__(256) void scan_write(const int* __restrict__ cnt,
                                                  const int* __restrict__ sums,
                                                  int* __restrict__ rowptr, int N, int E) {
    __shared__ int lds[256];
    int base = blockIdx.x * 1024;
    int off = sums[blockIdx.x];
    for (int c = 0; c < 4; ++c) {
        int idx = base + c * 256 + threadIdx.x;
        int v = (idx < N) ? cnt[idx] : 0;
        lds[threadIdx.x] = v;
        __syncthreads();
        for (int d = 1; d < 256; d <<= 1) {
            int t = (threadIdx.x >= d) ? lds[threadIdx.x - d] : 0;
            __syncthreads();
            lds[threadIdx.x] += t;
            __syncthreads();
        }
        int incl = lds[threadIdx.x];
        if (idx < N) rowptr[idx] = off + incl - v;
        off += lds[255];
        __syncthreads();
    }
    if (blockIdx.x == 0 && threadIdx.x == 0) rowptr[N] = E;
}

__global__ void fill_kernel(const int* __restrict__ src, const int* __restrict__ dst,
                            const int* __restrict__ rowptr, int* __restrict__ cur,
                            int* __restrict__ csr, int E) {
    int e = blockIdx.x * blockDim.x + threadIdx.x;
    if (e < E) {
        int d = dst[e];
        int slot = rowptr[d] + atomicAdd(&cur[d], 1);
        csr[slot] = src[e];
    }
}

// =============== K1: g1 = (X[N,128] @ W1[128,64]) * dinv ===============

__global__ __launch_bounds__(256) void gemm1_kernel(const float* __restrict__ X,
                                                    const float* __restrict__ W,
                                                    const int* __restrict__ rowptr,
                                                    float* __restrict__ Y, int N) {
    __shared__ float Ws[128 * 64];   // 32 KB
    __shared__ float Xs[16][132];    // padded: bank = (4*row + k) % 32, conflict-free
    {
        const float4* Wv = (const float4*)W;
        float4* Wsv = (float4*)Ws;
        for (int i = threadIdx.x; i < 128 * 16; i += 256) Wsv[i] = Wv[i];
    }
    int row = threadIdx.x >> 4;
    int node0 = blockIdx.x * 16;
    int node = node0 + row;
    {
        const float4* Xv = (const float4*)(X + (size_t)node0 * 128);
        for (int i = threadIdx.x; i < 512; i += 256) {
            int r = i >> 5, kk = i & 31;
            if (node0 + r < N) *(float4*)&Xs[r][kk * 4] = Xv[(size_t)r * 32 + kk];
        }
    }
    __syncthreads();
    if (node >= N) return;
    int c = (threadIdx.x & 15) * 4;
    float4 acc = make_float4(0.f, 0.f, 0.f, 0.f);
#pragma unroll 16
    for (int k = 0; k < 128; ++k) {
        float xv = Xs[row][k];
        float4 wv = *(const float4*)&Ws[k * 64 + c];
        acc.x += xv * wv.x; acc.y += xv * wv.y;
        acc.z += xv * wv.z; acc.w += xv * wv.w;
    }
    float w = rsqrtf((float)(rowptr[node + 1] - rowptr[node]) + 1.0f);
    acc.x *= w; acc.y *= w; acc.z *= w; acc.w *= w;
    *(float4*)&Y[(size_t)node * 64 + c] = acc;
}

// =============== fused: h = relu(dinv*agg(g) + b); out = (h @ W) * dinv ===============

__global__ __launch_bounds__(256) void fused_layer_kernel(const float* __restrict__ g,
                                                          const int* __restrict__ rowptr,
                                                          const int* __restrict__ csr,
                                                          const float* __restrict__ bias,
                                                          const float* __restrict__ W,
                                                          float* __restrict__ out, int N) {
    __shared__ float Ws[64 * 64];    // 16 KB
    __shared__ float T[16][72];      // bank = (8*row + k) % 32, conflict-free
    {
        const float4* Wv = (const float4*)W;
        float4* Wsv = (float4*)Ws;
        for (int i = threadIdx.x; i < 64 * 16; i += 256) Wsv[i] = Wv[i];
    }
    int row = threadIdx.x >> 4;
    int node = blockIdx.x * 16 + row;
    int c = (threadIdx.x & 15) * 4;
    float dinv = 0.f;
    if (node < N) {
        int beg = rowptr[node], end = rowptr[node + 1];
        dinv = rsqrtf((float)(end - beg) + 1.0f);
        float4 acc = *(const float4*)&g[(size_t)node * 64 + c];   // self-loop
        int j = beg;
        for (; j + 4 <= end; j += 4) {
            int s0 = csr[j], s1 = csr[j + 1], s2 = csr[j + 2], s3 = csr[j + 3];
            float4 v0 = *(const float4*)&g[(size_t)s0 * 64 + c];
            float4 v1 = *(const float4*)&g[(size_t)s1 * 64 + c];
            float4 v2 = *(const float4*)&g[(size_t)s2 * 64 + c];
            float4 v3 = *(const float4*)&g[(size_t)s3 * 64 + c];
            acc.x += (v0.x + v1.x) + (v2.x + v3.x);
            acc.y += (v0.y + v1.y) + (v2.y + v3.y);
            acc.z += (v0.z + v1.z) + (v2.z + v3.z);
            acc.w += (v0.w + v1.w) + (v2.w + v3.w);
        }
        for (; j < end; ++j) {
            int s = csr[j];
            float4 v = *(const float4*)&g[(size_t)s * 64 + c];
            acc.x += v.x; acc.y += v.y; acc.z += v.z; acc.w += v.w;
        }
        float4 bb = *(const float4*)&bias[c];
        T[row][c + 0] = fmaxf(acc.x * dinv + bb.x, 0.f);
        T[row][c + 1] = fmaxf(acc.y * dinv + bb.y, 0.f);
        T[row][c + 2] = fmaxf(acc.z * dinv + bb.z, 0.f);
        T[row][c + 3] = fmaxf(acc.w * dinv + bb.w, 0.f);
    }
    __syncthreads();
    if (node >= N) return;
    float4 o = make_float4(0.f, 0.f, 0.f, 0.f);
#pragma unroll 16
    for (int k = 0; k < 64; ++k) {
        float tv = T[row][k];
        float4 wv = *(const float4*)&Ws[k * 64 + c];
        o.x += tv * wv.x; o.y += tv * wv.y;
        o.z += tv * wv.z; o.w += tv * wv.w;
    }
    o.x *= dinv; o.y *= dinv; o.z *= dinv; o.w *= dinv;
    *(float4*)&out[(size_t)node * 64 + c] = o;
}

// =============== K4: h3 = dinv*agg(g3) + b3;  s_node = h3 . Wl ===============

__global__ __launch_bounds__(256) void agg_dot_kernel(const float* __restrict__ g,
                                                      const int* __restrict__ rowptr,
                                                      const int* __restrict__ csr,
                                                      const float* __restrict__ bias,
                                                      const float* __restrict__ Wl,
                                                      float* __restrict__ s_node, int N) {
    int t = blockIdx.x * blockDim.x + threadIdx.x;
    int node = t >> 4;
    if (node >= N) return;
    int c = (t & 15) * 4;
    int beg = rowptr[node], end = rowptr[node + 1];
    float dinv = rsqrtf((float)(end - beg) + 1.0f);
    float4 acc = *(const float4*)&g[(size_t)node * 64 + c];
    int j = beg;
    for (; j + 4 <= end; j += 4) {
        int s0 = csr[j], s1 = csr[j + 1], s2 = csr[j + 2], s3 = csr[j + 3];
        float4 v0 = *(const float4*)&g[(size_t)s0 * 64 + c];
        float4 v1 = *(const float4*)&g[(size_t)s1 * 64 + c];
        float4 v2 = *(const float4*)&g[(size_t)s2 * 64 + c];
        float4 v3 = *(const float4*)&g[(size_t)s3 * 64 + c];
        acc.x += (v0.x + v1.x) + (v2.x + v3.x);
        acc.y += (v0.y + v1.y) + (v2.y + v3.y);
        acc.z += (v0.z + v1.z) + (v2.z + v3.z);
        acc.w += (v0.w + v1.w) + (v2.w + v3.w);
    }
    for (; j < end; ++j) {
        int s = csr[j];
        float4 v = *(const float4*)&g[(size_t)s * 64 + c];
        acc.x += v.x; acc.y += v.y; acc.z += v.z; acc.w += v.w;
    }
    float4 bb = *(const float4*)&bias[c];
    float4 wl = *(const float4*)&Wl[c];
    float s = (acc.x * dinv + bb.x) * wl.x + (acc.y * dinv + bb.y) * wl.y +
              (acc.z * dinv + bb.z) * wl.z + (acc.w * dinv + bb.w) * wl.w;
    s += __shfl_xor(s, 1);
    s += __shfl_xor(s, 2);
    s += __shfl_xor(s, 4);
    s += __shfl_xor(s, 8);
    if ((threadIdx.x & 15) == 0) s_node[node] = s;
}

// =============== K5: per-graph mean over sorted batch + bl ===============

__device__ __forceinline__ int lower_bound_dev(const int* __restrict__ a, int n, int v) {
    int lo = 0, hi = n;
    while (lo < hi) { int mid = (lo + hi) >> 1; if (a[mid] < v) lo = mid + 1; else hi = mid; }
    return lo;
}

__global__ void pool_out_kernel(const float* __restrict__ s_node, const int* __restrict__ batch,
                                const float* __restrict__ bl, float* __restrict__ out, int N) {
    int gidx = blockIdx.x;
    int lo = lower_bound_dev(batch, N, gidx);
    int hi = lower_bound_dev(batch, N, gidx + 1);
    float s = 0.f;
    for (int i = lo + threadIdx.x; i < hi; i += 64) s += s_node[i];
    for (int d = 32; d; d >>= 1) s += __shfl_down(s, d);
    if (threadIdx.x == 0) out[gidx] = s / fmaxf((float)(hi - lo), 1.0f) + bl[0];
}

// =============== launcher ===============

extern "C" void kernel_launch(void* const* d_in, const int* in_sizes, int n_in,
                              void* d_out, int out_size, void* d_ws, size_t ws_size,
                              hipStream_t stream) {
    const float* x   = (const float*)d_in[0];
    const int*   ei  = (const int*)d_in[1];
    const int*   bat = (const int*)d_in[2];
    const float* W1  = (const float*)d_in[3];
    const float* b1  = (const float*)d_in[4];
    const float* W2  = (const float*)d_in[5];
    const float* b2  = (const float*)d_in[6];
    const float* W3  = (const float*)d_in[7];
    const float* b3  = (const float*)d_in[8];
    const float* Wl  = (const float*)d_in[9];
    const float* bl  = (const float*)d_in[10];

    const int N = in_sizes[0] / 128;   // 100000
    const int E = in_sizes[1] / 2;     // 1600000
    const int G = out_size;            // 1000

    const int* src = ei;
    const int* dst = ei + E;

    // workspace layout (cnt reused as s_node after CSR build)
    int*   cnt    = (int*)d_ws;                        // N: histogram -> cursor -> s_node
    int*   rowptr = cnt + N;                           // N+1
    int*   sums   = rowptr + (N + 1);                  // 1024
    int*   csr    = sums + 1024;                       // E
    float* bufA   = (float*)(csr + E);                 // N*64
    float* bufB   = bufA + (size_t)N * 64;             // N*64
    float* s_node = (float*)cnt;

    const int nb = (N + 1023) / 1024;

    // ---- CSR build ----
    hipMemsetAsync(cnt, 0, (size_t)N * sizeof(int), stream);
    hist_kernel<<<(E + 255) / 256, 256, 0, stream>>>(dst, cnt, E);
    scan_sums<<<nb, 256, 0, stream>>>(cnt, sums, N);
    scan_offsets<<<1, 64, 0, stream>>>(sums, nb);
    scan_write<<<nb, 256, 0, stream>>>(cnt, sums, rowptr, N, E);
    hipMemsetAsync(cnt, 0, (size_t)N * sizeof(int), stream);
    fill_kernel<<<(E + 255) / 256, 256, 0, stream>>>(src, dst, rowptr, cnt, csr, E);

    const int tileGrid = (N + 15) / 16;
    const int aggGrid  = (int)(((size_t)N * 16 + 255) / 256);

    gemm1_kernel<<<tileGrid, 256, 0, stream>>>(x, W1, rowptr, bufA, N);
    fused_layer_kernel<<<tileGrid, 256, 0, stream>>>(bufA, rowptr, csr, b1, W2, bufB, N);
    fused_layer_kernel<<<tileGrid, 256, 0, stream>>>(bufB, rowptr, csr, b2, W3, bufA, N);
    agg_dot_kernel<<<aggGrid, 256, 0, stream>>>(bufA, rowptr, csr, b3, Wl, s_node, N);
    pool_out_kernel<<<G, 64, 0, stream>>>(s_node, bat, bl, (float*)d_out, N);
}

// Round 5
// 493.519 us; speedup vs baseline: 8.4931x; 1.0046x over previous
//
#include <hip/hip_runtime.h>
#include <stdint.h>

#define NPB 128   // nodes per CSR bucket (phase-A/B binning)

// =============== CSR build ===============

__global__ void hist_kernel(const int* __restrict__ dst, int* __restrict__ cnt, int E) {
    int i = blockIdx.x * blockDim.x + threadIdx.x;
    if (i < E) atomicAdd(&cnt[dst[i]], 1);
}

__global__ void scan_sums(const int* __restrict__ cnt, int* __restrict__ sums, int N) {
    __shared__ int lds[4];
    int base = blockIdx.x * 1024;
    int s = 0;
    for (int i = threadIdx.x; i < 1024; i += 256) {
        int idx = base + i;
        if (idx < N) s += cnt[idx];
    }
    for (int d = 32; d; d >>= 1) s += __shfl_down(s, d);
    int wid = threadIdx.x >> 6;
    if ((threadIdx.x & 63) == 0) lds[wid] = s;
    __syncthreads();
    if (threadIdx.x == 0) sums[blockIdx.x] = lds[0] + lds[1] + lds[2] + lds[3];
}

__global__ void scan_offsets(int* __restrict__ sums, int nb) {
    if (threadIdx.x == 0 && blockIdx.x == 0) {
        int run = 0;
        for (int i = 0; i < nb; ++i) { int v = sums[i]; sums[i] = run; run += v; }
    }
}

__global__ __launch_bounds__(256) void scan_write(const int* __restrict__ cnt,
                                                  const int* __restrict__ sums,
                                                  int* __restrict__ rowptr, int N, int E) {
    __shared__ int lds[256];
    int base = blockIdx.x * 1024;
    int off = sums[blockIdx.x];
    for (int c = 0; c < 4; ++c) {
        int idx = base + c * 256 + threadIdx.x;
        int v = (idx < N) ? cnt[idx] : 0;
        lds[threadIdx.x] = v;
        __syncthreads();
        for (int d = 1; d < 256; d <<= 1) {
            int t = (threadIdx.x >= d) ? lds[threadIdx.x - d] : 0;
            __syncthreads();
            lds[threadIdx.x] += t;
            __syncthreads();
        }
        int incl = lds[threadIdx.x];
        if (idx < N) rowptr[idx] = off + incl - v;
        off += lds[255];
        __syncthreads();
    }
    if (blockIdx.x == 0 && threadIdx.x == 0) rowptr[N] = E;
}

// Phase A: bucket-group edges. bucket b's region in `pairs` is
// [rowptr[b*NPB], rowptr[(b+1)*NPB]) — contiguous, cursor-sequential writes.
__global__ void binfill_kernel(const int* __restrict__ src, const int* __restrict__ dst,
                               const int* __restrict__ rowptr, int* __restrict__ bcur,
                               int2* __restrict__ pairs, int E) {
    int e = blockIdx.x * blockDim.x + threadIdx.x;
    if (e >= E) return;
    int d = dst[e];
    int b = d >> 7;                                   // d / NPB
    int pos = rowptr[b << 7] + atomicAdd(&bcur[b << 4], 1);  // bcur padded: 1 cursor / 64B line
    pairs[pos] = make_int2(src[e], d);
}

// Phase B: per-bucket fine scatter via LDS cursors; writes confined to ~8KB window.
__global__ __launch_bounds__(256) void scatter_fine_kernel(const int2* __restrict__ pairs,
                                                           const int* __restrict__ rowptr,
                                                           int* __restrict__ csr, int N) {
    __shared__ int curs[NPB];
    int base = blockIdx.x * NPB;
    int top = min(base + NPB, N);
    if (threadIdx.x < top - base) curs[threadIdx.x] = rowptr[base + threadIdx.x];
    __syncthreads();
    int beg = rowptr[base], end = rowptr[top];
    for (int j = beg + (int)threadIdx.x; j < end; j += 256) {
        int2 p = pairs[j];
        int slot = atomicAdd(&curs[p.y - base], 1);
        csr[slot] = p.x;
    }
}

// =============== K1: g1 = (X[N,128] @ W1[128,64]) * dinv ===============

__global__ __launch_bounds__(256) void gemm1_kernel(const float* __restrict__ X,
                                                    const float* __restrict__ W,
                                                    const int* __restrict__ rowptr,
                                                    float* __restrict__ Y, int N) {
    __shared__ float Ws[128 * 64];   // 32 KB
    __shared__ float Xs[16][132];
    {
        const float4* Wv = (const float4*)W;
        float4* Wsv = (float4*)Ws;
        for (int i = threadIdx.x; i < 128 * 16; i += 256) Wsv[i] = Wv[i];
    }
    int row = threadIdx.x >> 4;
    int node0 = blockIdx.x * 16;
    int node = node0 + row;
    {
        const float4* Xv = (const float4*)(X + (size_t)node0 * 128);
        for (int i = threadIdx.x; i < 512; i += 256) {
            int r = i >> 5, kk = i & 31;
            if (node0 + r < N) *(float4*)&Xs[r][kk * 4] = Xv[(size_t)r * 32 + kk];
        }
    }
    __syncthreads();
    if (node >= N) return;
    int c = (threadIdx.x & 15) * 4;
    float4 acc = make_float4(0.f, 0.f, 0.f, 0.f);
#pragma unroll 16
    for (int k = 0; k < 128; ++k) {
        float xv = Xs[row][k];
        float4 wv = *(const float4*)&Ws[k * 64 + c];
        acc.x += xv * wv.x; acc.y += xv * wv.y;
        acc.z += xv * wv.z; acc.w += xv * wv.w;
    }
    float w = rsqrtf((float)(rowptr[node + 1] - rowptr[node]) + 1.0f);
    acc.x *= w; acc.y *= w; acc.z *= w; acc.w *= w;
    *(float4*)&Y[(size_t)node * 64 + c] = acc;
}

// =============== fused: h = relu(dinv*agg(g) + b); out = (h @ W) * dinv ===============

__global__ __launch_bounds__(256) void fused_layer_kernel(const float* __restrict__ g,
                                                          const int* __restrict__ rowptr,
                                                          const int* __restrict__ csr,
                                                          const float* __restrict__ bias,
                                                          const float* __restrict__ W,
                                                          float* __restrict__ out, int N) {
    __shared__ float Ws[64 * 64];    // 16 KB
    __shared__ float T[16][72];
    {
        const float4* Wv = (const float4*)W;
        float4* Wsv = (float4*)Ws;
        for (int i = threadIdx.x; i < 64 * 16; i += 256) Wsv[i] = Wv[i];
    }
    int row = threadIdx.x >> 4;
    int node = blockIdx.x * 16 + row;
    int c = (threadIdx.x & 15) * 4;
    float dinv = 0.f;
    if (node < N) {
        int beg = rowptr[node], end = rowptr[node + 1];
        dinv = rsqrtf((float)(end - beg) + 1.0f);
        float4 acc = *(const float4*)&g[(size_t)node * 64 + c];   // self-loop
        int j = beg;
        for (; j + 4 <= end; j += 4) {
            int s0 = csr[j], s1 = csr[j + 1], s2 = csr[j + 2], s3 = csr[j + 3];
            float4 v0 = *(const float4*)&g[(size_t)s0 * 64 + c];
            float4 v1 = *(const float4*)&g[(size_t)s1 * 64 + c];
            float4 v2 = *(const float4*)&g[(size_t)s2 * 64 + c];
            float4 v3 = *(const float4*)&g[(size_t)s3 * 64 + c];
            acc.x += (v0.x + v1.x) + (v2.x + v3.x);
            acc.y += (v0.y + v1.y) + (v2.y + v3.y);
            acc.z += (v0.z + v1.z) + (v2.z + v3.z);
            acc.w += (v0.w + v1.w) + (v2.w + v3.w);
        }
        for (; j < end; ++j) {
            int s = csr[j];
            float4 v = *(const float4*)&g[(size_t)s * 64 + c];
            acc.x += v.x; acc.y += v.y; acc.z += v.z; acc.w += v.w;
        }
        float4 bb = *(const float4*)&bias[c];
        T[row][c + 0] = fmaxf(acc.x * dinv + bb.x, 0.f);
        T[row][c + 1] = fmaxf(acc.y * dinv + bb.y, 0.f);
        T[row][c + 2] = fmaxf(acc.z * dinv + bb.z, 0.f);
        T[row][c + 3] = fmaxf(acc.w * dinv + bb.w, 0.f);
    }
    __syncthreads();
    if (node >= N) return;
    float4 o = make_float4(0.f, 0.f, 0.f, 0.f);
#pragma unroll 16
    for (int k = 0; k < 64; ++k) {
        float tv = T[row][k];
        float4 wv = *(const float4*)&Ws[k * 64 + c];
        o.x += tv * wv.x; o.y += tv * wv.y;
        o.z += tv * wv.z; o.w += tv * wv.w;
    }
    o.x *= dinv; o.y *= dinv; o.z *= dinv; o.w *= dinv;
    *(float4*)&out[(size_t)node * 64 + c] = o;
}

// =============== K4: h3 = dinv*agg(g3) + b3;  s_node = h3 . Wl ===============

__global__ __launch_bounds__(256) void agg_dot_kernel(const float* __restrict__ g,
                                                      const int* __restrict__ rowptr,
                                                      const int* __restrict__ csr,
                                                      const float* __restrict__ bias,
                                                      const float* __restrict__ Wl,
                                                      float* __restrict__ s_node, int N) {
    int t = blockIdx.x * blockDim.x + threadIdx.x;
    int node = t >> 4;
    if (node >= N) return;
    int c = (t & 15) * 4;
    int beg = rowptr[node], end = rowptr[node + 1];
    float dinv = rsqrtf((float)(end - beg) + 1.0f);
    float4 acc = *(const float4*)&g[(size_t)node * 64 + c];
    int j = beg;
    for (; j + 4 <= end; j += 4) {
        int s0 = csr[j], s1 = csr[j + 1], s2 = csr[j + 2], s3 = csr[j + 3];
        float4 v0 = *(const float4*)&g[(size_t)s0 * 64 + c];
        float4 v1 = *(const float4*)&g[(size_t)s1 * 64 + c];
        float4 v2 = *(const float4*)&g[(size_t)s2 * 64 + c];
        float4 v3 = *(const float4*)&g[(size_t)s3 * 64 + c];
        acc.x += (v0.x + v1.x) + (v2.x + v3.x);
        acc.y += (v0.y + v1.y) + (v2.y + v3.y);
        acc.z += (v0.z + v1.z) + (v2.z + v3.z);
        acc.w += (v0.w + v1.w) + (v2.w + v3.w);
    }
    for (; j < end; ++j) {
        int s = csr[j];
        float4 v = *(const float4*)&g[(size_t)s * 64 + c];
        acc.x += v.x; acc.y += v.y; acc.z += v.z; acc.w += v.w;
    }
    float4 bb = *(const float4*)&bias[c];
    float4 wl = *(const float4*)&Wl[c];
    float s = (acc.x * dinv + bb.x) * wl.x + (acc.y * dinv + bb.y) * wl.y +
              (acc.z * dinv + bb.z) * wl.z + (acc.w * dinv + bb.w) * wl.w;
    s += __shfl_xor(s, 1);
    s += __shfl_xor(s, 2);
    s += __shfl_xor(s, 4);
    s += __shfl_xor(s, 8);
    if ((threadIdx.x & 15) == 0) s_node[node] = s;
}

// =============== K5: per-graph mean over sorted batch + bl ===============

__device__ __forceinline__ int lower_bound_dev(const int* __restrict__ a, int n, int v) {
    int lo = 0, hi = n;
    while (lo < hi) { int mid = (lo + hi) >> 1; if (a[mid] < v) lo = mid + 1; else hi = mid; }
    return lo;
}

__global__ void pool_out_kernel(const float* __restrict__ s_node, const int* __restrict__ batch,
                                const float* __restrict__ bl, float* __restrict__ out, int N) {
    int gidx = blockIdx.x;
    int lo = lower_bound_dev(batch, N, gidx);
    int hi = lower_bound_dev(batch, N, gidx + 1);
    float s = 0.f;
    for (int i = lo + threadIdx.x; i < hi; i += 64) s += s_node[i];
    for (int d = 32; d; d >>= 1) s += __shfl_down(s, d);
    if (threadIdx.x == 0) out[gidx] = s / fmaxf((float)(hi - lo), 1.0f) + bl[0];
}

// =============== launcher ===============

extern "C" void kernel_launch(void* const* d_in, const int* in_sizes, int n_in,
                              void* d_out, int out_size, void* d_ws, size_t ws_size,
                              hipStream_t stream) {
    const float* x   = (const float*)d_in[0];
    const int*   ei  = (const int*)d_in[1];
    const int*   bat = (const int*)d_in[2];
    const float* W1  = (const float*)d_in[3];
    const float* b1  = (const float*)d_in[4];
    const float* W2  = (const float*)d_in[5];
    const float* b2  = (const float*)d_in[6];
    const float* W3  = (const float*)d_in[7];
    const float* b3  = (const float*)d_in[8];
    const float* Wl  = (const float*)d_in[9];
    const float* bl  = (const float*)d_in[10];

    const int N = in_sizes[0] / 128;   // 100000
    const int E = in_sizes[1] / 2;     // 1600000
    const int G = out_size;            // 1000

    const int* src = ei;
    const int* dst = ei + E;

    const int NB = (N + NPB - 1) / NPB;        // buckets
    const int Np = (N + 4) & ~3;               // padded N+1 for alignment

    // workspace layout (16B-aligned segments)
    int*   cnt    = (int*)d_ws;                // N       : hist -> (later) s_node
    int*   rowptr = cnt + N;                   // Np
    int*   sums   = rowptr + Np;               // 1024
    int*   bcur   = sums + 1024;               // NB*16 (padded cursors, 1/line)
    int*   csr    = bcur + (size_t)NB * 16;    // E
    float* bufA   = (float*)(csr + E);         // N*64
    float* bufB   = bufA + (size_t)N * 64;     // N*64
    float* s_node = (float*)cnt;
    int2*  pairs  = (int2*)bufA;               // aliases bufA: dead until gemm1

    const int nb = (N + 1023) / 1024;

    // ---- CSR build ----
    hipMemsetAsync(cnt, 0, (size_t)N * sizeof(int), stream);
    hipMemsetAsync(bcur, 0, (size_t)NB * 16 * sizeof(int), stream);
    hist_kernel<<<(E + 255) / 256, 256, 0, stream>>>(dst, cnt, E);
    scan_sums<<<nb, 256, 0, stream>>>(cnt, sums, N);
    scan_offsets<<<1, 64, 0, stream>>>(sums, nb);
    scan_write<<<nb, 256, 0, stream>>>(cnt, sums, rowptr, N, E);
    binfill_kernel<<<(E + 255) / 256, 256, 0, stream>>>(src, dst, rowptr, bcur, pairs, E);
    scatter_fine_kernel<<<NB, 256, 0, stream>>>(pairs, rowptr, csr, N);

    const int tileGrid = (N + 15) / 16;
    const int aggGrid  = (int)(((size_t)N * 16 + 255) / 256);

    gemm1_kernel<<<tileGrid, 256, 0, stream>>>(x, W1, rowptr, bufA, N);
    fused_layer_kernel<<<tileGrid, 256, 0, stream>>>(bufA, rowptr, csr, b1, W2, bufB, N);
    fused_layer_kernel<<<tileGrid, 256, 0, stream>>>(bufB, rowptr, csr, b2, W3, bufA, N);
    agg_dot_kernel<<<aggGrid, 256, 0, stream>>>(bufA, rowptr, csr, b3, Wl, s_node, N);
    pool_out_kernel<<<G, 64, 0, stream>>>(s_node, bat, bl, (float*)d_out, N);
}

// Round 6
// 462.151 us; speedup vs baseline: 9.0696x; 1.0679x over previous
//
#include <hip/hip_runtime.h>
#include <stdint.h>

#define BKT 1024   // nodes per coarse bucket (phase A)
#define SUB 128    // nodes per fine tile   (phase B)
#define EPB 4096   // edges per partition block

// =============== per-node histogram + rowptr (unchanged) ===============

__global__ void hist_kernel(const int* __restrict__ dst, int* __restrict__ cnt, int E) {
    int i = blockIdx.x * blockDim.x + threadIdx.x;
    if (i < E) atomicAdd(&cnt[dst[i]], 1);
}

__global__ void scan_sums(const int* __restrict__ cnt, int* __restrict__ sums, int N) {
    __shared__ int lds[4];
    int base = blockIdx.x * 1024;
    int s = 0;
    for (int i = threadIdx.x; i < 1024; i += 256) {
        int idx = base + i;
        if (idx < N) s += cnt[idx];
    }
    for (int d = 32; d; d >>= 1) s += __shfl_down(s, d);
    int wid = threadIdx.x >> 6;
    if ((threadIdx.x & 63) == 0) lds[wid] = s;
    __syncthreads();
    if (threadIdx.x == 0) sums[blockIdx.x] = lds[0] + lds[1] + lds[2] + lds[3];
}

__global__ void scan_offsets(int* __restrict__ sums, int nb) {
    if (threadIdx.x == 0 && blockIdx.x == 0) {
        int run = 0;
        for (int i = 0; i < nb; ++i) { int v = sums[i]; sums[i] = run; run += v; }
    }
}

__global__ __launch_bounds__(256) void scan_write(const int* __restrict__ cnt,
                                                  const int* __restrict__ sums,
                                                  int* __restrict__ rowptr, int N, int E) {
    __shared__ int lds[256];
    int base = blockIdx.x * 1024;
    int off = sums[blockIdx.x];
    for (int c = 0; c < 4; ++c) {
        int idx = base + c * 256 + threadIdx.x;
        int v = (idx < N) ? cnt[idx] : 0;
        lds[threadIdx.x] = v;
        __syncthreads();
        for (int d = 1; d < 256; d <<= 1) {
            int t = (threadIdx.x >= d) ? lds[threadIdx.x - d] : 0;
            __syncthreads();
            lds[threadIdx.x] += t;
            __syncthreads();
        }
        int incl = lds[threadIdx.x];
        if (idx < N) rowptr[idx] = off + incl - v;
        off += lds[255];
        __syncthreads();
    }
    if (blockIdx.x == 0 && threadIdx.x == 0) rowptr[N] = E;
}

// =============== Phase A: LDS-staged counting-sort partition by dst>>10 ===============
// Each block owns EPB edges; per-(block,bucket) output runs are contiguous and
// written by consecutive lanes -> full-line coalesced writes.

__global__ __launch_bounds__(256) void partition_kernel(const int* __restrict__ src,
                                                        const int* __restrict__ dst,
                                                        const int* __restrict__ rowptr,
                                                        int* __restrict__ gbcur,
                                                        int2* __restrict__ pairs,
                                                        int E, int NBK) {
    __shared__ int2 stage[EPB];          // 32 KB
    __shared__ int  hist[128], offs[129], gbase[128], lcur[128];
    int base = blockIdx.x * EPB;
    int cntE = min(EPB, E - base);
    if (threadIdx.x < 128) hist[threadIdx.x] = 0;
    __syncthreads();
    // pass 1: histogram
    for (int i = threadIdx.x; i < cntE; i += 256) {
        int b = dst[base + i] >> 10;
        atomicAdd(&hist[b], 1);
    }
    __syncthreads();
    // exclusive scan (NBK <= 128, serial by thread 0 — negligible)
    if (threadIdx.x == 0) {
        int run = 0;
        for (int b = 0; b < NBK; ++b) { offs[b] = run; run += hist[b]; }
        offs[NBK] = run;
    }
    __syncthreads();
    // reserve global runs: one atomic per (block,bucket)
    if (threadIdx.x < NBK) {
        int b = threadIdx.x;
        int h = hist[b];
        if (h > 0) gbase[b] = rowptr[b << 10] + atomicAdd(&gbcur[b << 4], h);
        lcur[b] = offs[b];
    }
    __syncthreads();
    // pass 2: stage in bucket order
    for (int i = threadIdx.x; i < cntE; i += 256) {
        int e = base + i;
        int d = dst[e];
        int b = d >> 10;
        int slot = atomicAdd(&lcur[b], 1);
        stage[slot] = make_int2(src[e], d);
    }
    __syncthreads();
    // write out: consecutive j -> consecutive global addresses within a run
    int total = offs[NBK];
    for (int j = threadIdx.x; j < total; j += 256) {
        // upper_bound over offs to find bucket of slot j
        int lo = 0, hi = NBK;
        while (lo < hi) { int mid = (lo + hi) >> 1; if (offs[mid + 1] <= j) lo = mid + 1; else hi = mid; }
        pairs[gbase[lo] + (j - offs[lo])] = stage[j];
    }
}

// =============== Phase B: per-128-node tile scatter (csr window private to block) ===============

__global__ __launch_bounds__(256) void subscatter_kernel(const int2* __restrict__ pairs,
                                                         const int* __restrict__ rowptr,
                                                         int* __restrict__ csr, int N) {
    __shared__ int curs[SUB];
    int sbase = blockIdx.x * SUB;                 // sub-tile node base
    int top = min(sbase + SUB, N);
    if (threadIdx.x < top - sbase) curs[threadIdx.x] = rowptr[sbase + threadIdx.x];
    __syncthreads();
    int parent = sbase >> 10;                     // coarse bucket
    int pbeg = rowptr[parent << 10];
    int pend = rowptr[min((parent + 1) << 10, N)];
    for (int j = pbeg + (int)threadIdx.x; j < pend; j += 256) {
        int2 p = pairs[j];
        unsigned local = (unsigned)(p.y - sbase);
        if (local < SUB) {
            int slot = atomicAdd(&curs[local], 1);
            csr[slot] = p.x;
        }
    }
}

// =============== K1: g1 = (X[N,128] @ W1[128,64]) * dinv ===============

__global__ __launch_bounds__(256) void gemm1_kernel(const float* __restrict__ X,
                                                    const float* __restrict__ W,
                                                    const int* __restrict__ rowptr,
                                                    float* __restrict__ Y, int N) {
    __shared__ float Ws[128 * 64];   // 32 KB
    __shared__ float Xs[16][132];
    {
        const float4* Wv = (const float4*)W;
        float4* Wsv = (float4*)Ws;
        for (int i = threadIdx.x; i < 128 * 16; i += 256) Wsv[i] = Wv[i];
    }
    int row = threadIdx.x >> 4;
    int node0 = blockIdx.x * 16;
    int node = node0 + row;
    {
        const float4* Xv = (const float4*)(X + (size_t)node0 * 128);
        for (int i = threadIdx.x; i < 512; i += 256) {
            int r = i >> 5, kk = i & 31;
            if (node0 + r < N) *(float4*)&Xs[r][kk * 4] = Xv[(size_t)r * 32 + kk];
        }
    }
    __syncthreads();
    if (node >= N) return;
    int c = (threadIdx.x & 15) * 4;
    float4 acc = make_float4(0.f, 0.f, 0.f, 0.f);
#pragma unroll 16
    for (int k = 0; k < 128; ++k) {
        float xv = Xs[row][k];
        float4 wv = *(const float4*)&Ws[k * 64 + c];
        acc.x += xv * wv.x; acc.y += xv * wv.y;
        acc.z += xv * wv.z; acc.w += xv * wv.w;
    }
    float w = rsqrtf((float)(rowptr[node + 1] - rowptr[node]) + 1.0f);
    acc.x *= w; acc.y *= w; acc.z *= w; acc.w *= w;
    *(float4*)&Y[(size_t)node * 64 + c] = acc;
}

// =============== fused: h = relu(dinv*agg(g) + b); out = (h @ W) * dinv ===============

__global__ __launch_bounds__(256) void fused_layer_kernel(const float* __restrict__ g,
                                                          const int* __restrict__ rowptr,
                                                          const int* __restrict__ csr,
                                                          const float* __restrict__ bias,
                                                          const float* __restrict__ W,
                                                          float* __restrict__ out, int N) {
    __shared__ float Ws[64 * 64];    // 16 KB
    __shared__ float T[16][72];
    {
        const float4* Wv = (const float4*)W;
        float4* Wsv = (float4*)Ws;
        for (int i = threadIdx.x; i < 64 * 16; i += 256) Wsv[i] = Wv[i];
    }
    int row = threadIdx.x >> 4;
    int node = blockIdx.x * 16 + row;
    int c = (threadIdx.x & 15) * 4;
    float dinv = 0.f;
    if (node < N) {
        int beg = rowptr[node], end = rowptr[node + 1];
        dinv = rsqrtf((float)(end - beg) + 1.0f);
        float4 acc = *(const float4*)&g[(size_t)node * 64 + c];   // self-loop
        int j = beg;
        for (; j + 4 <= end; j += 4) {
            int s0 = csr[j], s1 = csr[j + 1], s2 = csr[j + 2], s3 = csr[j + 3];
            float4 v0 = *(const float4*)&g[(size_t)s0 * 64 + c];
            float4 v1 = *(const float4*)&g[(size_t)s1 * 64 + c];
            float4 v2 = *(const float4*)&g[(size_t)s2 * 64 + c];
            float4 v3 = *(const float4*)&g[(size_t)s3 * 64 + c];
            acc.x += (v0.x + v1.x) + (v2.x + v3.x);
            acc.y += (v0.y + v1.y) + (v2.y + v3.y);
            acc.z += (v0.z + v1.z) + (v2.z + v3.z);
            acc.w += (v0.w + v1.w) + (v2.w + v3.w);
        }
        for (; j < end; ++j) {
            int s = csr[j];
            float4 v = *(const float4*)&g[(size_t)s * 64 + c];
            acc.x += v.x; acc.y += v.y; acc.z += v.z; acc.w += v.w;
        }
        float4 bb = *(const float4*)&bias[c];
        T[row][c + 0] = fmaxf(acc.x * dinv + bb.x, 0.f);
        T[row][c + 1] = fmaxf(acc.y * dinv + bb.y, 0.f);
        T[row][c + 2] = fmaxf(acc.z * dinv + bb.z, 0.f);
        T[row][c + 3] = fmaxf(acc.w * dinv + bb.w, 0.f);
    }
    __syncthreads();
    if (node >= N) return;
    float4 o = make_float4(0.f, 0.f, 0.f, 0.f);
#pragma unroll 16
    for (int k = 0; k < 64; ++k) {
        float tv = T[row][k];
        float4 wv = *(const float4*)&Ws[k * 64 + c];
        o.x += tv * wv.x; o.y += tv * wv.y;
        o.z += tv * wv.z; o.w += tv * wv.w;
    }
    o.x *= dinv; o.y *= dinv; o.z *= dinv; o.w *= dinv;
    *(float4*)&out[(size_t)node * 64 + c] = o;
}

// =============== K4: h3 = dinv*agg(g3) + b3;  s_node = h3 . Wl ===============

__global__ __launch_bounds__(256) void agg_dot_kernel(const float* __restrict__ g,
                                                      const int* __restrict__ rowptr,
                                                      const int* __restrict__ csr,
                                                      const float* __restrict__ bias,
                                                      const float* __restrict__ Wl,
                                                      float* __restrict__ s_node, int N) {
    int t = blockIdx.x * blockDim.x + threadIdx.x;
    int node = t >> 4;
    if (node >= N) return;
    int c = (t & 15) * 4;
    int beg = rowptr[node], end = rowptr[node + 1];
    float dinv = rsqrtf((float)(end - beg) + 1.0f);
    float4 acc = *(const float4*)&g[(size_t)node * 64 + c];
    int j = beg;
    for (; j + 4 <= end; j += 4) {
        int s0 = csr[j], s1 = csr[j + 1], s2 = csr[j + 2], s3 = csr[j + 3];
        float4 v0 = *(const float4*)&g[(size_t)s0 * 64 + c];
        float4 v1 = *(const float4*)&g[(size_t)s1 * 64 + c];
        float4 v2 = *(const float4*)&g[(size_t)s2 * 64 + c];
        float4 v3 = *(const float4*)&g[(size_t)s3 * 64 + c];
        acc.x += (v0.x + v1.x) + (v2.x + v3.x);
        acc.y += (v0.y + v1.y) + (v2.y + v3.y);
        acc.z += (v0.z + v1.z) + (v2.z + v3.z);
        acc.w += (v0.w + v1.w) + (v2.w + v3.w);
    }
    for (; j < end; ++j) {
        int s = csr[j];
        float4 v = *(const float4*)&g[(size_t)s * 64 + c];
        acc.x += v.x; acc.y += v.y; acc.z += v.z; acc.w += v.w;
    }
    float4 bb = *(const float4*)&bias[c];
    float4 wl = *(const float4*)&Wl[c];
    float s = (acc.x * dinv + bb.x) * wl.x + (acc.y * dinv + bb.y) * wl.y +
              (acc.z * dinv + bb.z) * wl.z + (acc.w * dinv + bb.w) * wl.w;
    s += __shfl_xor(s, 1);
    s += __shfl_xor(s, 2);
    s += __shfl_xor(s, 4);
    s += __shfl_xor(s, 8);
    if ((threadIdx.x & 15) == 0) s_node[node] = s;
}

// =============== K5: per-graph mean over sorted batch + bl ===============

__device__ __forceinline__ int lower_bound_dev(const int* __restrict__ a, int n, int v) {
    int lo = 0, hi = n;
    while (lo < hi) { int mid = (lo + hi) >> 1; if (a[mid] < v) lo = mid + 1; else hi = mid; }
    return lo;
}

__global__ void pool_out_kernel(const float* __restrict__ s_node, const int* __restrict__ batch,
                                const float* __restrict__ bl, float* __restrict__ out, int N) {
    int gidx = blockIdx.x;
    int lo = lower_bound_dev(batch, N, gidx);
    int hi = lower_bound_dev(batch, N, gidx + 1);
    float s = 0.f;
    for (int i = lo + threadIdx.x; i < hi; i += 64) s += s_node[i];
    for (int d = 32; d; d >>= 1) s += __shfl_down(s, d);
    if (threadIdx.x == 0) out[gidx] = s / fmaxf((float)(hi - lo), 1.0f) + bl[0];
}

// =============== launcher ===============

extern "C" void kernel_launch(void* const* d_in, const int* in_sizes, int n_in,
                              void* d_out, int out_size, void* d_ws, size_t ws_size,
                              hipStream_t stream) {
    const float* x   = (const float*)d_in[0];
    const int*   ei  = (const int*)d_in[1];
    const int*   bat = (const int*)d_in[2];
    const float* W1  = (const float*)d_in[3];
    const float* b1  = (const float*)d_in[4];
    const float* W2  = (const float*)d_in[5];
    const float* b2  = (const float*)d_in[6];
    const float* W3  = (const float*)d_in[7];
    const float* b3  = (const float*)d_in[8];
    const float* Wl  = (const float*)d_in[9];
    const float* bl  = (const float*)d_in[10];

    const int N = in_sizes[0] / 128;   // 100000
    const int E = in_sizes[1] / 2;     // 1600000
    const int G = out_size;            // 1000

    const int* src = ei;
    const int* dst = ei + E;

    const int NBK  = (N + BKT - 1) / BKT;      // coarse buckets (98)
    const int NSUB = (N + SUB - 1) / SUB;      // fine tiles (782)
    const int Np = (N + 4) & ~3;

    // workspace layout
    int*   cnt    = (int*)d_ws;                // N   : hist -> (later) s_node
    int*   rowptr = cnt + N;                   // Np
    int*   sums   = rowptr + Np;               // 1024
    int*   gbcur  = sums + 1024;               // NBK*16 padded cursors
    int*   csr    = gbcur + (size_t)NBK * 16;  // E
    float* bufA   = (float*)(csr + E);         // N*64
    float* bufB   = bufA + (size_t)N * 64;     // N*64
    float* s_node = (float*)cnt;
    int2*  pairs  = (int2*)bufA;               // aliases bufA (dead until gemm1)

    const int nb = (N + 1023) / 1024;

    // ---- rowptr ----
    hipMemsetAsync(cnt, 0, (size_t)N * sizeof(int), stream);
    hipMemsetAsync(gbcur, 0, (size_t)NBK * 16 * sizeof(int), stream);
    hist_kernel<<<(E + 255) / 256, 256, 0, stream>>>(dst, cnt, E);
    scan_sums<<<nb, 256, 0, stream>>>(cnt, sums, N);
    scan_offsets<<<1, 64, 0, stream>>>(sums, nb);
    scan_write<<<nb, 256, 0, stream>>>(cnt, sums, rowptr, N, E);

    // ---- two-phase CSR fill ----
    partition_kernel<<<(E + EPB - 1) / EPB, 256, 0, stream>>>(src, dst, rowptr, gbcur, pairs, E, NBK);
    subscatter_kernel<<<NSUB, 256, 0, stream>>>(pairs, rowptr, csr, N);

    const int tileGrid = (N + 15) / 16;
    const int aggGrid  = (int)(((size_t)N * 16 + 255) / 256);

    gemm1_kernel<<<tileGrid, 256, 0, stream>>>(x, W1, rowptr, bufA, N);
    fused_layer_kernel<<<tileGrid, 256, 0, stream>>>(bufA, rowptr, csr, b1, W2, bufB, N);
    fused_layer_kernel<<<tileGrid, 256, 0, stream>>>(bufB, rowptr, csr, b2, W3, bufA, N);
    agg_dot_kernel<<<aggGrid, 256, 0, stream>>>(bufA, rowptr, csr, b3, Wl, s_node, N);
    pool_out_kernel<<<G, 64, 0, stream>>>(s_node, bat, bl, (float*)d_out, N);
}